// Round 1
// baseline (1366.323 us; speedup 1.0000x reference)
//
#include <hip/hip_runtime.h>
#include <hip/hip_cooperative_groups.h>
#include <math.h>

namespace cg = cooperative_groups;

#define NWG 64
#define NTH 256
#define NPTS 4096
#define HW 64

struct Sched { float e[64]; int n; };

// Workspace layout (floats):
//   a_log [4096], b_log [4096], pot [4][4096], tT [4][64][64] (c, xi, yj), fpot [4][4096]
__global__ __launch_bounds__(NTH) void crowd_kernel(const float* __restrict__ pred,
                                                    const float* __restrict__ gt,
                                                    float* __restrict__ out,
                                                    float* __restrict__ ws,
                                                    Sched sc) {
    cg::grid_group grid = cg::this_grid();
    const int tid = threadIdx.x;
    const int wg  = blockIdx.x;
    const int gidx = wg * NTH + tid;

    float* a_log = ws;
    float* b_log = ws + NPTS;
    float* pot   = ws + 2 * NPTS;   // [4][NPTS]
    float* tT    = ws + 6 * NPTS;   // [4][HW][HW]  index: c*NPTS + xi*HW + yj
    float* fpot  = ws + 10 * NPTS;  // [4][NPTS]

    // ---- init: logs + zero potentials ----
    if (gidx < NPTS) {
        a_log[gidx] = __logf(pred[gidx]);
        b_log[gidx] = __logf(gt[gidx]);
        pot[0 * NPTS + gidx] = 0.f;
        pot[1 * NPTS + gidx] = 0.f;
        pot[2 * NPTS + gidx] = 0.f;
        pot[3 * NPTS + gidx] = 0.f;
    }
    grid.sync();

    const float rho = 0.01f;  // REACH^2
    const int c  = wg & 3;    // channel: 0=f_ba 1=g_ab 2=f_aa 3=g_bb
    const int rg = wg >> 2;   // group of 4 rows (pass1) / 4 cols (pass2)
    const int lr = tid >> 6;  // 0..3 local row/col
    const int lx = tid & 63;  // 0..63

    // h = base_log + pot[src]/eps
    const float* base = (c == 1 || c == 2) ? a_log : b_log;
    const int src = (c == 0) ? 1 : ((c == 1) ? 0 : c);

    __shared__ float sh[4][HW];

    const int n_iters = sc.n + 2;  // init + n scan steps + final extrapolation
    for (int it = 0; it < n_iters; ++it) {
        const float eps = (it == 0) ? sc.e[0] : ((it <= sc.n) ? sc.e[it - 1] : 0.04f);
        const float inv_eps = 1.0f / eps;
        const float inv2e = 0.5f * inv_eps;
        const float lam = rho / (rho + eps);

        // ---- pass 1: LSE over xj within each row yj ----
        {
            const int yj = rg * 4 + lr;
            const int idx = yj * HW + lx;
            sh[lr][lx] = base[idx] + pot[src * NPTS + idx] * inv_eps;
        }
        __syncthreads();
        {
            const int yj = rg * 4 + lr;
            const int xi = lx;
            float m = -1e30f;
            #pragma unroll
            for (int xj = 0; xj < HW; ++xj) {
                float d = (float)(xi - xj);
                float v = sh[lr][xj] - d * d * inv2e;
                m = fmaxf(m, v);
            }
            float s = 0.f;
            #pragma unroll
            for (int xj = 0; xj < HW; ++xj) {
                float d = (float)(xi - xj);
                float v = sh[lr][xj] - d * d * inv2e;
                s += __expf(v - m);
            }
            tT[c * NPTS + xi * HW + yj] = m + __logf(s);  // transposed store
        }
        grid.sync();

        // ---- pass 2: LSE over yj within each column xi; update potential ----
        {
            const int xi = rg * 4 + lr;
            sh[lr][lx] = tT[c * NPTS + xi * HW + lx];
        }
        __syncthreads();
        {
            const int xi = rg * 4 + lr;
            const int yi = lx;
            float m = -1e30f;
            #pragma unroll
            for (int yj = 0; yj < HW; ++yj) {
                float d = (float)(yi - yj);
                float v = sh[lr][yj] - d * d * inv2e;
                m = fmaxf(m, v);
            }
            float s = 0.f;
            #pragma unroll
            for (int yj = 0; yj < HW; ++yj) {
                float d = (float)(yi - yj);
                float v = sh[lr][yj] - d * d * inv2e;
                s += __expf(v - m);
            }
            const float val = lam * (-eps * (m + __logf(s)));
            const int oi = yi * HW + xi;
            if (it == 0)          pot[c * NPTS + oi] = val;               // init assign
            else if (it <= sc.n)  pot[c * NPTS + oi] = 0.5f * (pot[c * NPTS + oi] + val);  // averaged
            else                  fpot[c * NPTS + oi] = val;              // final extrapolation
        }
        grid.sync();
    }

    // ---- final reduction (block 0 only) ----
    if (wg == 0) {
        float d_sum = 0.f, sa = 0.f, sb = 0.f, s1 = 0.f, s2 = 0.f;
        const float inv_rho = 100.f;  // 1/rho
        for (int i = tid; i < NPTS; i += NTH) {
            float a = pred[i], b = gt[i];
            float df = a - b;
            d_sum += df * df;
            sa += a; sb += b;
            s1 += a * (__expf(-fpot[2 * NPTS + i] * inv_rho) - __expf(-fpot[0 * NPTS + i] * inv_rho));
            s2 += b * (__expf(-fpot[3 * NPTS + i] * inv_rho) - __expf(-fpot[1 * NPTS + i] * inv_rho));
        }
        __shared__ float red[5][4];
        float vals[5] = {d_sum, sa, sb, s1, s2};
        #pragma unroll
        for (int k = 0; k < 5; ++k) {
            float v = vals[k];
            #pragma unroll
            for (int off = 32; off >= 1; off >>= 1) v += __shfl_down(v, off, 64);
            if ((tid & 63) == 0) red[k][tid >> 6] = v;
        }
        __syncthreads();
        if (tid == 0) {
            float dm = 0, A = 0, B = 0, S1 = 0, S2 = 0;
            #pragma unroll
            for (int w4 = 0; w4 < 4; ++w4) {
                dm += red[0][w4]; A += red[1][w4]; B += red[2][w4];
                S1 += red[3][w4]; S2 += red[4][w4];
            }
            const float density = dm / (float)NPTS;
            const float count = fabsf(A - B);
            const float w = 0.01f + 0.5f * 0.04f;  // rho + eps_fin/2 = 0.03
            out[0] = density + count + 0.1f * (w * (S1 + S2));
        }
    }
}

static void build_sched(Sched* s) {
    // geomloss epsilon_schedule, P=2: [diam^2] + exp(arange(2ln d, 2ln 0.2, 2ln 0.9)) + [0.04]
    const double diam = sqrt(63.0 * 63.0 + 63.0 * 63.0);
    const double start = 2.0 * log(diam);
    const double stop  = 2.0 * log(0.2);
    const double step  = 2.0 * log(0.9);
    int n = 0;
    s->e[n++] = (float)(diam * diam);
    for (int k = 0; n < 63; ++k) {
        double v = start + step * (double)k;
        if (v <= stop) break;
        s->e[n++] = (float)exp(v);
    }
    s->e[n++] = 0.04f;  // BLUR^2
    s->n = n;           // = 60
}

extern "C" void kernel_launch(void* const* d_in, const int* in_sizes, int n_in,
                              void* d_out, int out_size, void* d_ws, size_t ws_size,
                              hipStream_t stream) {
    const float* pred = (const float*)d_in[0];
    const float* gt   = (const float*)d_in[1];
    // d_in[2] (gt_blur_map) is unused by the reference loss.
    float* out = (float*)d_out;
    float* ws  = (float*)d_ws;

    Sched sc;
    build_sched(&sc);

    void* args[] = {(void*)&pred, (void*)&gt, (void*)&out, (void*)&ws, (void*)&sc};
    hipLaunchCooperativeKernel((void*)crowd_kernel, dim3(NWG), dim3(NTH), args, 0, stream);
}

// Round 2
// 600.993 us; speedup vs baseline: 2.2734x; 2.2734x over previous
//
#include <hip/hip_runtime.h>
#include <hip/hip_cooperative_groups.h>
#include <math.h>

#define NWG 32           // 4 channels x 8 col-groups
#define NTH 512          // 8 columns x 64 rows
#define NPTS 4096
#define HW 64

struct Sched { float e[64]; int n; };

#define AGENT __HIP_MEMORY_SCOPE_AGENT

// Workspace layout (floats):
//   potbuf [2][4][4096]  (double-buffered potentials)      offset 0
//   fpot   [4][4096]     (final extrapolated potentials)   offset 32768
//   barrier words (unsigned)                               offset 49152
#define POT_OFF  0
#define FPOT_OFF 32768
#define BAR_OFF  49152

__device__ __forceinline__ void bar_sync(unsigned* cnt, unsigned* phase,
                                         unsigned nparty, unsigned target) {
    __syncthreads();
    if (threadIdx.x == 0) {
        unsigned old = __hip_atomic_fetch_add(cnt, 1u, __ATOMIC_ACQ_REL, AGENT);
        if (old == nparty - 1u) {
            // all arrived: reset counter, then publish new phase (release)
            __hip_atomic_store(cnt, 0u, __ATOMIC_RELAXED, AGENT);
            __hip_atomic_fetch_add(phase, 1u, __ATOMIC_RELEASE, AGENT);
        } else {
            while (__hip_atomic_load(phase, __ATOMIC_ACQUIRE, AGENT) < target)
                __builtin_amdgcn_s_sleep(2);
        }
    }
    __syncthreads();
}

__global__ void init_bar_kernel(float* ws) {
    unsigned* bw = (unsigned*)(ws + BAR_OFF);
    if (threadIdx.x < 192) bw[threadIdx.x] = 0u;
}

__global__ __launch_bounds__(NTH) void crowd_main(const float* __restrict__ pred,
                                                  const float* __restrict__ gt,
                                                  float* __restrict__ ws,
                                                  Sched sc) {
    const int tid = threadIdx.x;
    const int wg  = blockIdx.x;
    const int c      = wg >> 3;   // channel: 0=f_ba 1=g_ab 2=f_aa 3=g_bb
    const int colgrp = wg & 7;    // owns columns [colgrp*8, colgrp*8+8)
    const int lxi = tid >> 6;     // 0..7 local column
    const int yv  = tid & 63;     // row (pass1) / output row yi (pass2)
    const int xi  = colgrp * 8 + lxi;
    const float xif = (float)xi;
    const float yvf = (float)yv;

    float* potbuf = ws + POT_OFF;    // [2][4][NPTS]
    float* fpot   = ws + FPOT_OFF;   // [4][NPTS]
    unsigned* bw  = (unsigned*)(ws + BAR_OFF);
    const int g = (c < 2) ? 0 : (c - 1);          // barrier group
    const unsigned nparty = (c < 2) ? 16u : 8u;
    unsigned* bcnt   = &bw[g * 64];
    unsigned* bphase = &bw[g * 64 + 16];

    // h = base_log + pot[src]/eps
    const float* basef = (c == 1 || c == 2) ? pred : gt;   // a-side vs b-side
    const int src = (c == 0) ? 1 : ((c == 1) ? 0 : c);

    __shared__ float bl[HW][HW + 1];      // base log field
    __shared__ float h[HW][HW + 1];       // h field for this iteration
    __shared__ float rowlse[HW][9];       // pass1 output: [yj][lxi]

    // ---- fill base log field ----
    #pragma unroll
    for (int k = 0; k < 8; ++k) {
        int idx = tid + k * NTH;
        bl[idx >> 6][idx & 63] = __logf(basef[idx]);
    }

    const float rho = 0.01f;  // REACH^2
    const int n_iters = sc.n + 2;   // init + n scan steps + final extrapolation

    for (int it = 0; it < n_iters; ++it) {
        const float eps = (it == 0) ? sc.e[0] : ((it <= sc.n) ? sc.e[it - 1] : 0.04f);
        const float inv_eps = 1.0f / eps;
        const float inv2e = 0.5f * inv_eps;
        const float lam = rho / (rho + eps);
        const int rb = (it + 1) & 1;    // read buffer  (holds it-1 values)
        const int wb = it & 1;          // write buffer

        // ---- build h field in LDS ----
        if (it == 0) {
            #pragma unroll
            for (int k = 0; k < 8; ++k) {
                int idx = tid + k * NTH;
                h[idx >> 6][idx & 63] = bl[idx >> 6][idx & 63];
            }
        } else {
            const float* psrc = potbuf + (rb * 4 + src) * NPTS;
            #pragma unroll
            for (int k = 0; k < 8; ++k) {
                int idx = tid + k * NTH;
                h[idx >> 6][idx & 63] = bl[idx >> 6][idx & 63] + psrc[idx] * inv_eps;
            }
        }
        __syncthreads();

        // ---- pass 1: row-LSE at (yj=yv, xi) over xj ----
        {
            float m = -1e30f;
            #pragma unroll
            for (int xj = 0; xj < HW; ++xj) {
                float d = xif - (float)xj;
                float v = h[yv][xj] - d * d * inv2e;
                m = fmaxf(m, v);
            }
            float s = 0.f;
            #pragma unroll
            for (int xj = 0; xj < HW; ++xj) {
                float d = xif - (float)xj;
                float v = h[yv][xj] - d * d * inv2e;
                s += __expf(v - m);
            }
            rowlse[yv][lxi] = m + __logf(s);
        }
        __syncthreads();

        // ---- pass 2: column-LSE at (yi=yv, xi) over yj; update potential ----
        {
            float m = -1e30f;
            #pragma unroll
            for (int yj = 0; yj < HW; ++yj) {
                float d = yvf - (float)yj;
                float v = rowlse[yj][lxi] - d * d * inv2e;
                m = fmaxf(m, v);
            }
            float s = 0.f;
            #pragma unroll
            for (int yj = 0; yj < HW; ++yj) {
                float d = yvf - (float)yj;
                float v = rowlse[yj][lxi] - d * d * inv2e;
                s += __expf(v - m);
            }
            const float val = lam * (-eps * (m + __logf(s)));
            const int oi = yv * HW + xi;
            if (it == 0) {
                potbuf[(wb * 4 + c) * NPTS + oi] = val;                 // init assign
            } else if (it <= sc.n) {
                float old = potbuf[(rb * 4 + c) * NPTS + oi];
                potbuf[(wb * 4 + c) * NPTS + oi] = 0.5f * (old + val);  // averaged
            } else {
                fpot[c * NPTS + oi] = val;                              // final extrapolation
            }
        }

        if (it <= sc.n) bar_sync(bcnt, bphase, nparty, (unsigned)(it + 1));
        else __syncthreads();   // harmless; keeps control flow uniform at exit
    }
}

__global__ __launch_bounds__(256) void crowd_reduce(const float* __restrict__ pred,
                                                    const float* __restrict__ gt,
                                                    const float* __restrict__ ws,
                                                    float* __restrict__ out) {
    const int tid = threadIdx.x;
    const float* fpot = ws + FPOT_OFF;
    float d_sum = 0.f, sa = 0.f, sb = 0.f, s1 = 0.f, s2 = 0.f;
    const float inv_rho = 100.f;  // 1/rho
    for (int i = tid; i < NPTS; i += 256) {
        float a = pred[i], b = gt[i];
        float df = a - b;
        d_sum += df * df;
        sa += a; sb += b;
        s1 += a * (__expf(-fpot[2 * NPTS + i] * inv_rho) - __expf(-fpot[0 * NPTS + i] * inv_rho));
        s2 += b * (__expf(-fpot[3 * NPTS + i] * inv_rho) - __expf(-fpot[1 * NPTS + i] * inv_rho));
    }
    __shared__ float red[5][4];
    float vals[5] = {d_sum, sa, sb, s1, s2};
    #pragma unroll
    for (int k = 0; k < 5; ++k) {
        float v = vals[k];
        #pragma unroll
        for (int off = 32; off >= 1; off >>= 1) v += __shfl_down(v, off, 64);
        if ((tid & 63) == 0) red[k][tid >> 6] = v;
    }
    __syncthreads();
    if (tid == 0) {
        float dm = 0, A = 0, B = 0, S1 = 0, S2 = 0;
        #pragma unroll
        for (int w4 = 0; w4 < 4; ++w4) {
            dm += red[0][w4]; A += red[1][w4]; B += red[2][w4];
            S1 += red[3][w4]; S2 += red[4][w4];
        }
        const float density = dm / (float)NPTS;
        const float count = fabsf(A - B);
        const float w = 0.01f + 0.5f * 0.04f;  // rho + eps_fin/2
        out[0] = density + count + 0.1f * (w * (S1 + S2));
    }
}

static void build_sched(Sched* s) {
    // geomloss epsilon_schedule, P=2: [diam^2] + exp(arange(2ln d, 2ln 0.2, 2ln 0.9)) + [0.04]
    const double diam = sqrt(63.0 * 63.0 + 63.0 * 63.0);
    const double start = 2.0 * log(diam);
    const double stop  = 2.0 * log(0.2);
    const double step  = 2.0 * log(0.9);
    int n = 0;
    s->e[n++] = (float)(diam * diam);
    for (int k = 0; n < 63; ++k) {
        double v = start + step * (double)k;
        if (v <= stop) break;
        s->e[n++] = (float)exp(v);
    }
    s->e[n++] = 0.04f;  // BLUR^2
    s->n = n;           // = 60
}

extern "C" void kernel_launch(void* const* d_in, const int* in_sizes, int n_in,
                              void* d_out, int out_size, void* d_ws, size_t ws_size,
                              hipStream_t stream) {
    const float* pred = (const float*)d_in[0];
    const float* gt   = (const float*)d_in[1];
    // d_in[2] (gt_blur_map) is unused by the reference loss.
    float* out = (float*)d_out;
    float* ws  = (float*)d_ws;

    Sched sc;
    build_sched(&sc);

    hipLaunchKernelGGL(init_bar_kernel, dim3(1), dim3(256), 0, stream, ws);

    void* args[] = {(void*)&pred, (void*)&gt, (void*)&ws, (void*)&sc};
    hipLaunchCooperativeKernel((void*)crowd_main, dim3(NWG), dim3(NTH), args, 0, stream);

    hipLaunchKernelGGL(crowd_reduce, dim3(1), dim3(256), 0, stream, pred, gt, ws, out);
}

// Round 3
// 539.886 us; speedup vs baseline: 2.5308x; 1.1132x over previous
//
#include <hip/hip_runtime.h>
#include <math.h>

#define NWG 32           // 4 channels x 8 col-groups
#define NTH 512          // 8 columns x 64 rows
#define NPTS 4096
#define HW 64

struct Sched { float e[64]; int n; };

#define AGENT __HIP_MEMORY_SCOPE_AGENT

// Workspace layout (floats):
//   potbuf [2][4][4096]  (double-buffered potentials, TRANSPOSED [c][x*64+y]) off 0
//   fpot   [4][4096]     (final extrapolated potentials, transposed)          off 32768
//   barrier words (unsigned): arrive[3][16] stride 32, go[3] stride 32        off 49152
#define POT_OFF  0
#define FPOT_OFF 32768
#define BAR_OFF  49152

__global__ void init_bar_kernel(float* ws) {
    unsigned* bw = (unsigned*)(ws + BAR_OFF);
    int i = threadIdx.x;
    #pragma unroll
    for (int k = 0; k < 8; ++k) bw[i + k * 256] = 0u;
}

__device__ __forceinline__ void flag_barrier(unsigned* arrive, unsigned* go,
                                             int party, int nparty, unsigned t) {
    __syncthreads();
    if (threadIdx.x == 0) {
        __hip_atomic_store(arrive + party * 32, t, __ATOMIC_RELEASE, AGENT);
        if (party == 0) {
            if (nparty == 16) {
                bool all;
                do {
                    all = true;
                    #pragma unroll
                    for (int q = 0; q < 16; ++q)
                        all &= (__hip_atomic_load(arrive + q * 32, __ATOMIC_RELAXED, AGENT) >= t);
                } while (!all);
            } else {
                bool all;
                do {
                    all = true;
                    #pragma unroll
                    for (int q = 0; q < 8; ++q)
                        all &= (__hip_atomic_load(arrive + q * 32, __ATOMIC_RELAXED, AGENT) >= t);
                } while (!all);
            }
            __threadfence();
            __hip_atomic_store(go, t, __ATOMIC_RELEASE, AGENT);
        } else {
            while (__hip_atomic_load(go, __ATOMIC_RELAXED, AGENT) < t) {}
            __threadfence();
        }
    }
    __syncthreads();
}

__global__ __launch_bounds__(NTH) void crowd_main(const float* __restrict__ pred,
                                                  const float* __restrict__ gt,
                                                  float* __restrict__ ws,
                                                  Sched sc) {
    const int tid = threadIdx.x;
    const int wg  = blockIdx.x;
    const int c      = wg >> 3;   // channel: 0=f_ba 1=g_ab 2=f_aa 3=g_bb
    const int colgrp = wg & 7;    // owns columns [colgrp*8, colgrp*8+8)
    const int lxi = tid >> 6;     // 0..7 local column (wave-uniform)
    const int yv  = tid & 63;     // row index (= lane)
    const int xi  = (colgrp << 3) + lxi;
    const float xif = (float)xi;
    const float yvf = (float)yv;

    float* potbuf = ws + POT_OFF;    // [2][4][NPTS], transposed [x*64+y]
    float* fpot   = ws + FPOT_OFF;   // [4][NPTS], transposed
    unsigned* bw  = (unsigned*)(ws + BAR_OFF);
    const int g = (c < 2) ? 0 : (c - 1);          // barrier group
    const int nparty = (c < 2) ? 16 : 8;
    const int party  = (c < 2) ? ((c << 3) | colgrp) : colgrp;
    unsigned* arrive = bw + g * 512;
    unsigned* go     = bw + 1536 + g * 32;

    const float* basef = (c == 1 || c == 2) ? pred : gt;   // a-side vs b-side
    const int src = (c == 0) ? 1 : ((c == 1) ? 0 : c);

    __shared__ float bl[HW][HW + 1];      // base log field [row][col]
    __shared__ float h[HW][HW + 1];       // h field [row][col]
    __shared__ float rowlse[HW][9];       // pass1 output [row][local col]

    // ---- fill base log field ----
    #pragma unroll
    for (int k = 0; k < 8; ++k) {
        int idx = tid + k * NTH;
        bl[idx >> 6][idx & 63] = __logf(basef[idx]);
    }
    __syncthreads();

    const float rho = 0.01f;  // REACH^2
    const int n_iters = sc.n + 2;   // init + n scan steps + final extrapolation

    for (int it = 0; it < n_iters; ++it) {
        const float eps = (it == 0) ? sc.e[0] : ((it <= sc.n) ? sc.e[it - 1] : 0.04f);
        const float inv_eps = 1.0f / eps;
        const float inv2e = 0.5f * inv_eps;
        const float lam = rho / (rho + eps);
        const int rb = (it + 1) & 1;    // read buffer  (holds it-1 values)
        const int wb = it & 1;          // write buffer

        // truncation radius: terms beyond r are < e^-44 relative (negligible)
        int r = 63;
        {
            float re = __fsqrt_rn(88.f * eps);
            if (re < 62.f) r = (int)re + 1;
        }

        // ---- build h field in LDS (only needed columns when truncated) ----
        if (it == 0) {
            #pragma unroll
            for (int k = 0; k < 8; ++k) {
                int idx = tid + k * NTH;
                h[idx >> 6][idx & 63] = bl[idx >> 6][idx & 63];
            }
        } else {
            const float* psrc = potbuf + (rb * 4 + src) * NPTS;
            if (r >= 63) {
                #pragma unroll
                for (int k = 0; k < 8; ++k) {
                    int idx = tid + k * NTH;   // idx = x*64 + y
                    int x = idx >> 6, y = idx & 63;
                    h[y][x] = bl[y][x] + psrc[idx] * inv_eps;
                }
            } else {
                int cl = (colgrp << 3) - r; if (cl < 0) cl = 0;
                int ch = (colgrp << 3) + 7 + r; if (ch > 63) ch = 63;
                for (int xj = cl + lxi; xj <= ch; xj += 8)
                    h[yv][xj] = bl[yv][xj] + psrc[(xj << 6) + yv] * inv_eps;
            }
        }
        __syncthreads();

        // ---- pass 1: row-LSE at (row yv, col xi) over xj, center-shifted ----
        {
            const float m = h[yv][xi];
            float s = 0.f;
            if (r >= 63) {
                #pragma unroll 4
                for (int xj = 0; xj < HW; ++xj) {
                    float d = xif - (float)xj;
                    float v = h[yv][xj] - d * d * inv2e;
                    s += __expf(v - m);
                }
            } else {
                int lo = xi - r; if (lo < 0) lo = 0;
                int hi = xi + r; if (hi > 63) hi = 63;
                for (int xj = lo; xj <= hi; ++xj) {
                    float d = xif - (float)xj;
                    float v = h[yv][xj] - d * d * inv2e;
                    s += __expf(v - m);
                }
            }
            rowlse[yv][lxi] = m + __logf(s);
        }
        __syncthreads();

        // ---- pass 2: col-LSE at (row yv, col xi) over yj, center-shifted ----
        {
            const float m = rowlse[yv][lxi];
            float s = 0.f;
            if (r >= 63) {
                #pragma unroll 4
                for (int yj = 0; yj < HW; ++yj) {
                    float d = yvf - (float)yj;
                    float v = rowlse[yj][lxi] - d * d * inv2e;
                    s += __expf(v - m);
                }
            } else {
                for (int dd = -r; dd <= r; ++dd) {
                    int yj = yv + dd;
                    int yc = yj < 0 ? 0 : (yj > 63 ? 63 : yj);
                    float df = (float)dd;
                    float v = rowlse[yc][lxi] - df * df * inv2e;
                    v = (yj == yc) ? v : -1e30f;   // mask out-of-range -> exp = 0
                    s += __expf(v - m);
                }
            }
            const float val = lam * (-eps * (m + __logf(s)));
            const int oiT = (xi << 6) | yv;        // transposed, lanes contiguous
            if (it == 0) {
                potbuf[(wb * 4 + c) * NPTS + oiT] = val;
            } else if (it <= sc.n) {
                float old = potbuf[(rb * 4 + c) * NPTS + oiT];
                potbuf[(wb * 4 + c) * NPTS + oiT] = 0.5f * (old + val);
            } else {
                fpot[c * NPTS + oiT] = val;
            }
        }

        if (it <= sc.n) flag_barrier(arrive, go, party, nparty, (unsigned)(it + 1));
        else __syncthreads();
    }
}

__global__ __launch_bounds__(256) void crowd_reduce(const float* __restrict__ pred,
                                                    const float* __restrict__ gt,
                                                    const float* __restrict__ ws,
                                                    float* __restrict__ out) {
    const int tid = threadIdx.x;
    const float* fpot = ws + FPOT_OFF;
    float d_sum = 0.f, sa = 0.f, sb = 0.f, s1 = 0.f, s2 = 0.f;
    const float inv_rho = 100.f;  // 1/rho
    for (int i = tid; i < NPTS; i += 256) {
        int jT = ((i & 63) << 6) | (i >> 6);   // transposed fpot index
        float a = pred[i], b = gt[i];
        float df = a - b;
        d_sum += df * df;
        sa += a; sb += b;
        s1 += a * (__expf(-fpot[2 * NPTS + jT] * inv_rho) - __expf(-fpot[0 * NPTS + jT] * inv_rho));
        s2 += b * (__expf(-fpot[3 * NPTS + jT] * inv_rho) - __expf(-fpot[1 * NPTS + jT] * inv_rho));
    }
    __shared__ float red[5][4];
    float vals[5] = {d_sum, sa, sb, s1, s2};
    #pragma unroll
    for (int k = 0; k < 5; ++k) {
        float v = vals[k];
        #pragma unroll
        for (int off = 32; off >= 1; off >>= 1) v += __shfl_down(v, off, 64);
        if ((tid & 63) == 0) red[k][tid >> 6] = v;
    }
    __syncthreads();
    if (tid == 0) {
        float dm = 0, A = 0, B = 0, S1 = 0, S2 = 0;
        #pragma unroll
        for (int w4 = 0; w4 < 4; ++w4) {
            dm += red[0][w4]; A += red[1][w4]; B += red[2][w4];
            S1 += red[3][w4]; S2 += red[4][w4];
        }
        const float density = dm / (float)NPTS;
        const float count = fabsf(A - B);
        const float w = 0.01f + 0.5f * 0.04f;  // rho + eps_fin/2
        out[0] = density + count + 0.1f * (w * (S1 + S2));
    }
}

static void build_sched(Sched* s) {
    // geomloss epsilon_schedule, P=2: [diam^2] + exp(arange(2ln d, 2ln 0.2, 2ln 0.9)) + [0.04]
    const double diam = sqrt(63.0 * 63.0 + 63.0 * 63.0);
    const double start = 2.0 * log(diam);
    const double stop  = 2.0 * log(0.2);
    const double step  = 2.0 * log(0.9);
    int n = 0;
    s->e[n++] = (float)(diam * diam);
    for (int k = 0; n < 63; ++k) {
        double v = start + step * (double)k;
        if (v <= stop) break;
        s->e[n++] = (float)exp(v);
    }
    s->e[n++] = 0.04f;  // BLUR^2
    s->n = n;           // = 60
}

extern "C" void kernel_launch(void* const* d_in, const int* in_sizes, int n_in,
                              void* d_out, int out_size, void* d_ws, size_t ws_size,
                              hipStream_t stream) {
    const float* pred = (const float*)d_in[0];
    const float* gt   = (const float*)d_in[1];
    // d_in[2] (gt_blur_map) is unused by the reference loss.
    float* out = (float*)d_out;
    float* ws  = (float*)d_ws;

    Sched sc;
    build_sched(&sc);

    hipLaunchKernelGGL(init_bar_kernel, dim3(1), dim3(256), 0, stream, ws);

    void* args[] = {(void*)&pred, (void*)&gt, (void*)&ws, (void*)&sc};
    hipLaunchCooperativeKernel((void*)crowd_main, dim3(NWG), dim3(NTH), args, 0, stream);

    hipLaunchKernelGGL(crowd_reduce, dim3(1), dim3(256), 0, stream, pred, gt, ws, out);
}

// Round 4
// 233.970 us; speedup vs baseline: 5.8397x; 2.3075x over previous
//
#include <hip/hip_runtime.h>
#include <math.h>

#define NPTS 4096
#define LN64 4.1588830833596715f

typedef _Float16 half8 __attribute__((ext_vector_type(8)));
typedef _Float16 half4 __attribute__((ext_vector_type(4)));
typedef float f32x4 __attribute__((ext_vector_type(4)));

struct Sched { float e[64]; int n; };

#define MFMA16 __builtin_amdgcn_mfma_f32_16x16x32_f16

// ws layout: fpot [4][4096] fp32 at offset 0. Everything else lives in LDS/regs.
//
// Per iteration (all linear-domain, E scaled by 64 to stay in fp16 normal range):
//   E^T stacked [c*64+x][y] fp16 -> GEMM1: C1 = E^T x W  (y-convolution)
//   C1[c*64+x][y'] stored transposed -> T[c*64+y'][x]  (natural orientation)
//   GEMM2: C2 = T x W (x-convolution) -> C2[c*64+y][x'] = H[y][x'] (natural)
//   pot update in registers (fixed tile ownership); E-next written transposed.
// Blocks: 0 = {f_ba, g_ab} coupled pair (M=128); 1 = f_aa; 2 = g_bb. No
// inter-block communication at all -> plain launch, __syncthreads only.
__global__ __launch_bounds__(512) void crowd_main(const float* __restrict__ pred,
                                                  const float* __restrict__ gt,
                                                  float* __restrict__ ws,
                                                  Sched sc) {
    const int tid = threadIdx.x;
    const int wg  = blockIdx.x;          // 0: pair(c0,c1); 1: c2; 2: c3
    const int w   = tid >> 6;            // wave 0..7
    const int l   = tid & 63;
    const int ln  = l & 15;              // MFMA col-lane (m/n = lane&15)
    const int lg  = l >> 4;              // MFMA group (k-group / row-group)

    const bool active = (wg == 0) || (w < 4);
    const int tm = w;                          // tile row-block
    const int cl = (wg == 0) ? (tm >> 2) : 0;  // local channel (stack index)
    const int ch = (wg == 0) ? cl : (wg + 1);  // global channel 0..3
    const int y0 = ((tm & 3) << 4) + (lg << 2);   // owned 4 contiguous y's
    // channel bases: c0=f_ba: gt; c1=g_ab: pred; c2=f_aa: pred; c3=g_bb: gt
    const float* basef = (ch == 1 || ch == 2) ? pred : gt;

    __shared__ _Float16 Es[128][72];      // E^T stacked [c*64+x][y]
    __shared__ _Float16 Tb[128][72];      // T stacked   [c*64+y][x]
    __shared__ _Float16 Wm[64][72];       // W[j][i] (symmetric)
    __shared__ float potm[2][64][68];     // pot mirror [c][x][y] (pair only)

    float blv[4][4];   // log(base) at owned coords
    float pot[4][4];   // potentials at owned coords (registers are master copy)

    // ---- init: blv, pot=0, initial E (pot=0 -> E = 64*exp(bl)) ----
    if (active) {
        #pragma unroll
        for (int tn = 0; tn < 4; ++tn) {
            const int xc = tn * 16 + ln;
            #pragma unroll
            for (int r = 0; r < 4; ++r) {
                blv[tn][r] = __logf(basef[(y0 + r) * 64 + xc]);
                pot[tn][r] = 0.f;
                Es[cl * 64 + xc][y0 + r] = (_Float16)__expf(blv[tn][r] + LN64);
            }
        }
    }

    const float rho = 0.01f;
    const int n = sc.n;

    for (int it = 0; it <= n + 1; ++it) {
        const float eps   = (it == 0) ? sc.e[0] : ((it <= n) ? sc.e[it - 1] : 0.04f);
        const float inv2e = 0.5f / eps;
        const float lam   = rho / (rho + eps);
        const float eps_nxt = (it + 1 <= n) ? sc.e[it] : 0.04f;
        const float inv_eps_nxt = 1.0f / eps_nxt;

        // ---- build W for this eps (all 512 threads) ----
        {
            const int j = tid >> 3, ib = (tid & 7) * 9;
            #pragma unroll
            for (int q = 0; q < 9; ++q) {
                float d = (float)(ib + q - j);
                Wm[j][ib + q] = (_Float16)__expf(-d * d * inv2e);
            }
        }
        __syncthreads();   // Es (prev epilogue) + Wm visible

        // ---- B fragments of W (shared by both GEMMs) ----
        half8 wb0[4], wb1[4];
        if (active) {
            #pragma unroll
            for (int tn = 0; tn < 4; ++tn) {
                wb0[tn] = *(const half8*)&Wm[tn * 16 + ln][lg * 8];
                wb1[tn] = *(const half8*)&Wm[tn * 16 + ln][32 + lg * 8];
            }
        }

        // ---- GEMM1: C1 = Es x W -> transposed store into Tb ----
        if (active) {
            half8 a0 = *(const half8*)&Es[tm * 16 + ln][lg * 8];
            half8 a1 = *(const half8*)&Es[tm * 16 + ln][32 + lg * 8];
            #pragma unroll
            for (int tn = 0; tn < 4; ++tn) {
                f32x4 acc = {0.f, 0.f, 0.f, 0.f};
                acc = MFMA16(a0, wb0[tn], acc, 0, 0, 0);
                acc = MFMA16(a1, wb1[tn], acc, 0, 0, 0);
                half4 t4;
                t4[0] = (_Float16)acc[0]; t4[1] = (_Float16)acc[1];
                t4[2] = (_Float16)acc[2]; t4[3] = (_Float16)acc[3];
                // C1[c*64+x][y'] -> Tb[c*64+y'][x]; lane's 4 regs are x-contiguous
                *(half4*)&Tb[cl * 64 + tn * 16 + ln][((tm & 3) << 4) + (lg << 2)] = t4;
            }
        }
        __syncthreads();   // Tb visible

        // ---- GEMM2: C2 = Tb x W (natural orientation H[y][x']) ----
        f32x4 acc2[4];
        if (active) {
            half8 a0 = *(const half8*)&Tb[tm * 16 + ln][lg * 8];
            half8 a1 = *(const half8*)&Tb[tm * 16 + ln][32 + lg * 8];
            #pragma unroll
            for (int tn = 0; tn < 4; ++tn) {
                f32x4 acc = {0.f, 0.f, 0.f, 0.f};
                acc = MFMA16(a0, wb0[tn], acc, 0, 0, 0);
                acc = MFMA16(a1, wb1[tn], acc, 0, 0, 0);
                acc2[tn] = acc;
            }
        }

        // ---- epilogue: softmin value, pot update (regs), potm mirror ----
        if (active) {
            const float sce = -eps * lam;
            #pragma unroll
            for (int tn = 0; tn < 4; ++tn) {
                #pragma unroll
                for (int r = 0; r < 4; ++r) {
                    float val = sce * (__logf(acc2[tn][r]) - LN64);
                    if (it == 0)      pot[tn][r] = val;
                    else if (it <= n) pot[tn][r] = 0.5f * (pot[tn][r] + val);
                    else ws[ch * NPTS + (y0 + r) * 64 + tn * 16 + ln] = val;  // fpot
                }
                if (wg == 0 && it <= n) {
                    f32x4 p4 = {pot[tn][0], pot[tn][1], pot[tn][2], pot[tn][3]};
                    *(f32x4*)&potm[cl][tn * 16 + ln][y0] = p4;
                }
            }
        }
        __syncthreads();   // potm visible (uniform sync for all blocks)

        // ---- build E for next iteration (uses post-update pots, next eps) ----
        if (active && it <= n) {
            #pragma unroll
            for (int tn = 0; tn < 4; ++tn) {
                const int xc = tn * 16 + ln;
                float ps[4];
                if (wg == 0) {
                    f32x4 p4 = *(const f32x4*)&potm[1 - cl][xc][y0];
                    ps[0] = p4[0]; ps[1] = p4[1]; ps[2] = p4[2]; ps[3] = p4[3];
                } else {
                    ps[0] = pot[tn][0]; ps[1] = pot[tn][1];
                    ps[2] = pot[tn][2]; ps[3] = pot[tn][3];
                }
                half4 e4;
                #pragma unroll
                for (int r = 0; r < 4; ++r)
                    e4[r] = (_Float16)__expf(blv[tn][r] + ps[r] * inv_eps_nxt + LN64);
                *(half4*)&Es[cl * 64 + xc][y0] = e4;
            }
        }
    }
}

__global__ __launch_bounds__(256) void crowd_reduce(const float* __restrict__ pred,
                                                    const float* __restrict__ gt,
                                                    const float* __restrict__ ws,
                                                    float* __restrict__ out) {
    const int tid = threadIdx.x;
    const float* fpot = ws;
    float d_sum = 0.f, sa = 0.f, sb = 0.f, s1 = 0.f, s2 = 0.f;
    const float inv_rho = 100.f;
    for (int i = tid; i < NPTS; i += 256) {
        float a = pred[i], b = gt[i];
        float df = a - b;
        d_sum += df * df;
        sa += a; sb += b;
        s1 += a * (__expf(-fpot[2 * NPTS + i] * inv_rho) - __expf(-fpot[0 * NPTS + i] * inv_rho));
        s2 += b * (__expf(-fpot[3 * NPTS + i] * inv_rho) - __expf(-fpot[1 * NPTS + i] * inv_rho));
    }
    __shared__ float red[5][4];
    float vals[5] = {d_sum, sa, sb, s1, s2};
    #pragma unroll
    for (int k = 0; k < 5; ++k) {
        float v = vals[k];
        #pragma unroll
        for (int off = 32; off >= 1; off >>= 1) v += __shfl_down(v, off, 64);
        if ((tid & 63) == 0) red[k][tid >> 6] = v;
    }
    __syncthreads();
    if (tid == 0) {
        float dm = 0, A = 0, B = 0, S1 = 0, S2 = 0;
        #pragma unroll
        for (int w4 = 0; w4 < 4; ++w4) {
            dm += red[0][w4]; A += red[1][w4]; B += red[2][w4];
            S1 += red[3][w4]; S2 += red[4][w4];
        }
        const float density = dm / (float)NPTS;
        const float count = fabsf(A - B);
        const float wgt = 0.01f + 0.5f * 0.04f;  // rho + eps_fin/2
        out[0] = density + count + 0.1f * (wgt * (S1 + S2));
    }
}

static void build_sched(Sched* s) {
    // geomloss epsilon_schedule, P=2: [diam^2] + exp(arange(2ln d, 2ln 0.2, 2ln 0.9)) + [0.04]
    const double diam = sqrt(63.0 * 63.0 + 63.0 * 63.0);
    const double start = 2.0 * log(diam);
    const double stop  = 2.0 * log(0.2);
    const double step  = 2.0 * log(0.9);
    int n = 0;
    s->e[n++] = (float)(diam * diam);
    for (int k = 0; n < 63; ++k) {
        double v = start + step * (double)k;
        if (v <= stop) break;
        s->e[n++] = (float)exp(v);
    }
    s->e[n++] = 0.04f;  // BLUR^2
    s->n = n;           // = 60
}

extern "C" void kernel_launch(void* const* d_in, const int* in_sizes, int n_in,
                              void* d_out, int out_size, void* d_ws, size_t ws_size,
                              hipStream_t stream) {
    const float* pred = (const float*)d_in[0];
    const float* gt   = (const float*)d_in[1];
    // d_in[2] (gt_blur_map) is unused by the reference loss.
    float* out = (float*)d_out;
    float* ws  = (float*)d_ws;

    Sched sc;
    build_sched(&sc);

    hipLaunchKernelGGL(crowd_main, dim3(3), dim3(512), 0, stream, pred, gt, ws, sc);
    hipLaunchKernelGGL(crowd_reduce, dim3(1), dim3(256), 0, stream, pred, gt, ws, out);
}

// Round 5
// 185.752 us; speedup vs baseline: 7.3556x; 1.2596x over previous
//
#include <hip/hip_runtime.h>
#include <math.h>

#define NPTS 4096
#define LN64 4.1588830833596715f
#define AGENT __HIP_MEMORY_SCOPE_AGENT

typedef _Float16 half8 __attribute__((ext_vector_type(8)));
typedef _Float16 half4 __attribute__((ext_vector_type(4)));
typedef float f32x4 __attribute__((ext_vector_type(4)));

struct Sched { float e[64]; int n; };

#define MFMA16 __builtin_amdgcn_mfma_f32_16x16x32_f16

// One kernel, 3 blocks, zero cross-block sync during the anneal:
//   block 0: coupled pair {c0=f_ba, c1=g_ab}  (8 GEMM waves)
//   block 1: c2=f_aa (4 GEMM waves) -- READER: combines partials, writes out
//   block 2: c3=g_bb (4 GEMM waves)
// Per iteration (linear domain, E scaled by 64):
//   GEMM1: C1 = E x W (y-conv), transposed store -> Tb ; GEMM2: C2 = Tb x W.
//   Epilogue: val = -lam*eps*(log C2 - LN64); pot in regs; wave writes the
//   PARTNER channel's E directly (needs only partner-base log, preloaded).
// End: each block reduces sign*exp(blv - 100*val) -> scalar partial in ws;
// blocks 0/2 publish with device-scope release flags (ws poison 0xAA != 1),
// block 1 spins, combines with density+count, writes out[0].
__global__ __launch_bounds__(512) void crowd_main(const float* __restrict__ pred,
                                                  const float* __restrict__ gt,
                                                  float* __restrict__ ws,
                                                  float* __restrict__ out,
                                                  Sched sc) {
    const int tid = threadIdx.x;
    const int blk = blockIdx.x;
    const int w   = tid >> 6;
    const int l   = tid & 63;
    const int ln  = l & 15;
    const int lg  = l >> 4;

    const bool active = (blk == 0) || (w < 4);
    const int tmloc = w & 3;
    const int cl     = (blk == 0) ? (w >> 2) : 0;     // stack slot of own channel
    const int pstack = (blk == 0) ? (1 - cl) : 0;     // partner stack slot
    const int ch     = (blk == 0) ? cl : (blk + 1);   // global channel 0..3
    const int stackbase = cl << 6;
    const int y0 = (tmloc << 4) + (lg << 2);
    const int mrow = stackbase + (tmloc << 4) + ln;

    // base(partner(ch)): ch=0->pred, ch=1->gt, ch=2->pred, ch=3->gt
    const float* baseP = (ch == 0 || ch == 2) ? pred : gt;

    __shared__ _Float16 Es[128][72];
    __shared__ _Float16 Tb[128][72];
    __shared__ _Float16 Wm[64][72];
    __shared__ float red[4][8];

    float blv[4][4], pot[4][4];

    // ---- init: partner-base logs, pot=0, initial E of partner channel ----
    if (active) {
        #pragma unroll
        for (int tn = 0; tn < 4; ++tn) {
            const int xc = (tn << 4) + ln;
            half4 e4;
            #pragma unroll
            for (int r = 0; r < 4; ++r) {
                blv[tn][r] = __logf(baseP[((y0 + r) << 6) | xc]);
                pot[tn][r] = 0.f;
                e4[r] = (_Float16)__expf(blv[tn][r] + LN64);
            }
            *(half4*)&Es[(pstack << 6) + xc][y0] = e4;
        }
    }

    const int n = sc.n;

    for (int it = 0; it <= n + 1; ++it) {
        const float eps   = (it == 0) ? sc.e[0] : ((it <= n) ? sc.e[it - 1] : 0.04f);
        const float inv2e = 0.5f / eps;
        const float lam   = 0.01f / (0.01f + eps);
        const float sce   = -eps * lam;
        const float inv_eps_nxt = 1.0f / ((it + 1 <= n) ? sc.e[it] : 0.04f);

        // ---- W build: one aligned half8 store per thread ----
        {
            const int j  = tid >> 3;
            const int cb = (tid & 7) << 3;
            half8 w8;
            #pragma unroll
            for (int q = 0; q < 8; ++q) {
                float d = (float)(cb + q - j);
                w8[q] = (_Float16)__expf(-d * d * inv2e);
            }
            *(half8*)&Wm[j][cb] = w8;
        }
        __syncthreads();   // Wm + Es (prev E-build) visible

        f32x4 acc2[4];
        half8 wb0[4], wb1[4];
        if (active) {
            #pragma unroll
            for (int tn = 0; tn < 4; ++tn) {
                wb0[tn] = *(const half8*)&Wm[(tn << 4) + ln][lg << 3];
                wb1[tn] = *(const half8*)&Wm[(tn << 4) + ln][32 + (lg << 3)];
            }
            // GEMM1: C1 = Es x W -> transposed store into Tb
            half8 a0 = *(const half8*)&Es[mrow][lg << 3];
            half8 a1 = *(const half8*)&Es[mrow][32 + (lg << 3)];
            #pragma unroll
            for (int tn = 0; tn < 4; ++tn) {
                f32x4 acc = {0.f, 0.f, 0.f, 0.f};
                acc = MFMA16(a0, wb0[tn], acc, 0, 0, 0);
                acc = MFMA16(a1, wb1[tn], acc, 0, 0, 0);
                half4 t4;
                t4[0] = (_Float16)acc[0]; t4[1] = (_Float16)acc[1];
                t4[2] = (_Float16)acc[2]; t4[3] = (_Float16)acc[3];
                *(half4*)&Tb[stackbase + (tn << 4) + ln][y0] = t4;
            }
        }
        __syncthreads();   // Tb visible

        if (active) {
            // GEMM2: C2 = Tb x W
            half8 a0 = *(const half8*)&Tb[mrow][lg << 3];
            half8 a1 = *(const half8*)&Tb[mrow][32 + (lg << 3)];
            #pragma unroll
            for (int tn = 0; tn < 4; ++tn) {
                f32x4 acc = {0.f, 0.f, 0.f, 0.f};
                acc = MFMA16(a0, wb0[tn], acc, 0, 0, 0);
                acc = MFMA16(a1, wb1[tn], acc, 0, 0, 0);
                acc2[tn] = acc;
            }
            // epilogue: softmin value, pot update, partner E for next iter
            #pragma unroll
            for (int tn = 0; tn < 4; ++tn) {
                const int xc = (tn << 4) + ln;
                float vals[4];
                #pragma unroll
                for (int r = 0; r < 4; ++r)
                    vals[r] = sce * (__logf(acc2[tn][r]) - LN64);
                if (it == 0) {
                    #pragma unroll
                    for (int r = 0; r < 4; ++r) pot[tn][r] = vals[r];
                } else if (it <= n) {
                    #pragma unroll
                    for (int r = 0; r < 4; ++r) pot[tn][r] = 0.5f * (pot[tn][r] + vals[r]);
                } else {
                    #pragma unroll
                    for (int r = 0; r < 4; ++r) pot[tn][r] = vals[r];  // final extrapolation
                }
                if (it <= n) {
                    half4 e4;
                    #pragma unroll
                    for (int r = 0; r < 4; ++r)
                        e4[r] = (_Float16)__expf(blv[tn][r] + pot[tn][r] * inv_eps_nxt + LN64);
                    *(half4*)&Es[(pstack << 6) + xc][y0] = e4;
                }
            }
        }
    }

    // ---- in-block reduction ----
    float accP = 0.f, dsum = 0.f, sa = 0.f, sb = 0.f;
    if (active) {
        const float sgn = (blk == 0) ? -1.f : 1.f;   // f_ba/g_ab enter negatively
        #pragma unroll
        for (int tn = 0; tn < 4; ++tn)
            #pragma unroll
            for (int r = 0; r < 4; ++r)
                accP += sgn * __expf(blv[tn][r] - 100.f * pot[tn][r]);
    }
    if (blk == 1) {
        for (int i = tid; i < NPTS; i += 512) {
            float a = pred[i], b = gt[i], d = a - b;
            dsum += d * d; sa += a; sb += b;
        }
    }
    {
        float acc4[4] = {accP, dsum, sa, sb};
        #pragma unroll
        for (int k = 0; k < 4; ++k) {
            float v = acc4[k];
            #pragma unroll
            for (int off = 32; off >= 1; off >>= 1) v += __shfl_down(v, off, 64);
            if (l == 0) red[k][w] = v;
        }
    }
    __syncthreads();

    unsigned* uw = (unsigned*)ws;
    if (tid == 0) {
        float P = 0.f, D = 0.f, SA = 0.f, SB = 0.f;
        #pragma unroll
        for (int q = 0; q < 8; ++q) {
            P += red[0][q]; D += red[1][q]; SA += red[2][q]; SB += red[3][q];
        }
        if (blk == 0) {
            ws[0] = P;
            __threadfence();
            __hip_atomic_store(&uw[128], 1u, __ATOMIC_RELEASE, AGENT);
        } else if (blk == 2) {
            ws[64] = P;
            __threadfence();
            __hip_atomic_store(&uw[192], 1u, __ATOMIC_RELEASE, AGENT);
        } else {
            while (__hip_atomic_load(&uw[128], __ATOMIC_ACQUIRE, AGENT) != 1u)
                __builtin_amdgcn_s_sleep(2);
            while (__hip_atomic_load(&uw[192], __ATOMIC_ACQUIRE, AGENT) != 1u)
                __builtin_amdgcn_s_sleep(2);
            __threadfence();
            const float P0 = ws[0], P1 = ws[64];
            const float density = D * (1.0f / (float)NPTS);
            const float count = fabsf(SA - SB);
            out[0] = density + count + 0.1f * 0.03f * (P + P0 + P1);  // w = rho + eps_fin/2
        }
    }
}

static void build_sched(Sched* s) {
    // geomloss epsilon_schedule, P=2: [diam^2] + exp(arange(2ln d, 2ln 0.2, 2ln 0.9)) + [0.04]
    const double diam = sqrt(63.0 * 63.0 + 63.0 * 63.0);
    const double start = 2.0 * log(diam);
    const double stop  = 2.0 * log(0.2);
    const double step  = 2.0 * log(0.9);
    int n = 0;
    s->e[n++] = (float)(diam * diam);
    for (int k = 0; n < 63; ++k) {
        double v = start + step * (double)k;
        if (v <= stop) break;
        s->e[n++] = (float)exp(v);
    }
    s->e[n++] = 0.04f;  // BLUR^2
    s->n = n;           // = 62 entries total
}

extern "C" void kernel_launch(void* const* d_in, const int* in_sizes, int n_in,
                              void* d_out, int out_size, void* d_ws, size_t ws_size,
                              hipStream_t stream) {
    const float* pred = (const float*)d_in[0];
    const float* gt   = (const float*)d_in[1];
    // d_in[2] (gt_blur_map) is unused by the reference loss.
    float* out = (float*)d_out;
    float* ws  = (float*)d_ws;

    Sched sc;
    build_sched(&sc);

    hipLaunchKernelGGL(crowd_main, dim3(3), dim3(512), 0, stream, pred, gt, ws, out, sc);
}